// Round 2
// baseline (140.131 us; speedup 1.0000x reference)
//
#include <hip/hip_runtime.h>

#define NT 256
#define NB 2048   // NB*NT = 524288 threads; B=4M -> exactly 8 rows/thread

// R9: pure streaming, row-per-thread. R8 (LDS-staged, perfectly coalesced
// dwordx4) only moved 41.4->36.7us (~3.07 TB/s) -> intra-wave stride was
// NOT the limiter. R9 removes every remaining structural suspect at once:
//   - no nt (caching loads; nt may throttle outstanding non-allocating misses)
//   - no LDS staging, no per-tile barrier (no full-drain per 28KB of traffic)
//   - persistent grid-stride (no one-shot block churn)
//   - 3x scalar dword per row: 64 lanes at 12B stride cover 768B contiguous
//     = 12 unique lines/instr (~5.3 lanes/line) — same unique-line density
//     as unit stride; loads 2/3 merge onto in-flight lines in the TCP.
//   - unroll 4 -> 28 outstanding loads/wave; ~32 waves/CU (no LDS, low VGPR).
// If this still lands ~36us, the ~3.1 TB/s read-stream rate (== m13 copy's
// read half) is the hardware ceiling and we are at roofline.

// wmid chain (continuous): ramp [0,a), 1 [a,b], down (b,c), 0 [c,d], tail >d.
// tail = -1 + 2^(1 - t/d) (k = ln2/d). down = 1-(t-b)/(c-b) folded into fma.

__device__ __forceinline__ float loss_head(float p, float t) {
    int ap = (p>=150.0f)+(p>=500.0f)+(p>=1000.0f)+(p>=1800.0f)+(p>=2600.0f);
    int at = (t>=150.0f)+(t>=500.0f)+(t>=1000.0f)+(t>=1800.0f)+(t>=2600.0f);
    float wc = exp2f(fabsf((float)(ap-at)) * 0.13750352374993502f); // 1.1^|d|
    float wm = fmaxf(fminf(fminf(t*0.0125f, 1.0f), fmaf(t,-0.004f,7.0f)), 0.0f);
    float tail = exp2f(fmaf(t,-0.0005f,1.0f)) - 1.0f;
    wm = (t>2000.0f) ? tail : wm;
    wm += (p<0.0f) ? 2.0f : 1.0f;
    return fabsf(p-t)*wc*wm;
}

// AIS compare in scaled space: p*rs >= thr  <=>  p >= thr*s (rs = 1/s, v_rcp).
// wmid uses RAW t (reference scales only the AIS thresholds).
__device__ __forceinline__ float loss_chest(float p, float t, float rs) {
    float ps = p*rs, ts = t*rs;
    int ap = (ps>=22.0f)+(ps>=35.0f)+(ps>=45.0f)+(ps>=55.0f)+(ps>=65.0f);
    int at = (ts>=22.0f)+(ts>=35.0f)+(ts>=45.0f)+(ts>=55.0f)+(ts>=65.0f);
    float wc = exp2f(fabsf((float)(ap-at)) * 0.13750352374993502f);
    float wm = fmaxf(fminf(fminf(t*0.1f, 1.0f), fmaf(t,-0.1f,8.5f)), 0.0f);
    float tail = exp2f(fmaf(t,-0.01f,1.0f)) - 1.0f;
    wm = (t>100.0f) ? tail : wm;
    wm += (p<0.0f) ? 2.0f : 1.0f;
    return fabsf(p-t)*wc*wm;
}

__device__ __forceinline__ float loss_neck(float p, float t) {
    int ap = (p>=0.2f)+(p>=0.5f)+(p>=1.0f)+(p>=1.5f)+(p>=2.0f);
    int at = (t>=0.2f)+(t>=0.5f)+(t>=1.0f)+(t>=1.5f)+(t>=2.0f);
    float wc = exp2f(fabsf((float)(ap-at)) * 0.13750352374993502f);
    float wm = fmaxf(fminf(fminf(t*6.6666667f, 1.0f), fmaf(t,-5.0f,8.5f)), 0.0f);
    float tail = exp2f(fmaf(t,-0.52631579f,1.0f)) - 1.0f;
    wm = (t>1.9f) ? tail : wm;
    wm += (p<0.0f) ? 2.0f : 1.0f;
    return fabsf(p-t)*wc*wm;
}

__global__ __launch_bounds__(NT)
void weighted_loss_main(const float* __restrict__ pred,
                        const float* __restrict__ truth,
                        const int*   __restrict__ ot,
                        float* __restrict__ partial, int B) {
    const int g = blockIdx.x * NT + threadIdx.x;
    const int T = gridDim.x * NT;

    float acc = 0.0f;

    #pragma unroll 4
    for (int r = g; r < B; r += T) {           // 8 iters for B=4M
        float ph = pred[3*r],  pc = pred[3*r+1],  pn = pred[3*r+2];
        float th = truth[3*r], tc = truth[3*r+1], tn = truth[3*r+2];
        float rs = __builtin_amdgcn_rcpf(fmaf(0.1f,(float)ot[r],0.8f));
        acc += loss_head(ph,th) + loss_chest(pc,tc,rs) + loss_neck(pn,tn);
    }

    // wave (64) reduce then cross-wave via LDS
    #pragma unroll
    for (int off = 32; off > 0; off >>= 1) acc += __shfl_down(acc, off, 64);
    __shared__ float sm[NT / 64];
    const int lane = threadIdx.x & 63, wid = threadIdx.x >> 6;
    if (lane == 0) sm[wid] = acc;
    __syncthreads();
    if (threadIdx.x == 0) {
        float s = 0.0f;
        #pragma unroll
        for (int w = 0; w < NT / 64; ++w) s += sm[w];
        partial[blockIdx.x] = s;
    }
}

__global__ __launch_bounds__(1024)
void weighted_loss_reduce(const float* __restrict__ partial, int n,
                          float* __restrict__ out, float invB) {
    float acc = 0.0f;
    for (int i = threadIdx.x; i < n; i += blockDim.x) acc += partial[i];
    #pragma unroll
    for (int off = 32; off > 0; off >>= 1) acc += __shfl_down(acc, off, 64);
    __shared__ float sm[16];
    const int lane = threadIdx.x & 63, wid = threadIdx.x >> 6;
    if (lane == 0) sm[wid] = acc;
    __syncthreads();
    if (threadIdx.x == 0) {
        float s = 0.0f;
        #pragma unroll
        for (int w = 0; w < 16; ++w) s += sm[w];
        out[0] = s * invB;
    }
}

extern "C" void kernel_launch(void* const* d_in, const int* in_sizes, int n_in,
                              void* d_out, int out_size, void* d_ws, size_t ws_size,
                              hipStream_t stream) {
    const float* pred  = (const float*)d_in[0];   // (B,3) f32
    const float* truth = (const float*)d_in[1];   // (B,3) f32
    const int*   ot    = (const int*)d_in[2];     // (B,)  i32
    const int B = in_sizes[2];
    float* partial = (float*)d_ws;                // NB floats, fully overwritten

    weighted_loss_main<<<NB, NT, 0, stream>>>(pred, truth, ot, partial, B);
    weighted_loss_reduce<<<1, 1024, 0, stream>>>(partial, NB, (float*)d_out,
                                                 1.0f / (float)B);
}

// Round 3
// 135.346 us; speedup vs baseline: 1.0354x; 1.0354x over previous
//
#include <hip/hip_runtime.h>

#define NT 256
#define NB 4096   // NB*NT = 1048576 = B/4 quads -> exactly 1 quad/thread

// R10: R8 tile shape, but staging via __builtin_amdgcn_global_load_lds
// (width 16). Evidence so far: R7 (direct dwordx4) 2.72 TB/s, R8 (coalesced
// dwordx4 -> LDS) 3.07, R9 (scalar, no nt, no LDS) 2.62 — and the L3-WARM
// R9 run (hbm_bytes = 67 KB, fully cache-resident) ran the SAME 43-45us as
// cold. The read cap (~3.1 TB/s = 5 B/cyc/CU = m13 copy's read half) is
// source-agnostic -> it lives in the CU-side miss/return path, not HBM.
// global_load_lds is the one untested return path: TCP->LDS direct DMA, no
// VGPR writeback. Single-variable A/B vs R8: only the staging mechanism
// changes. LDS dest lds_p[k*NT+tid] is linear in lane (16B elems) — the
// wave-uniform-base + lane*16 layout the instruction requires (m104).

typedef float vf4 __attribute__((ext_vector_type(4)));
typedef int   vi4 __attribute__((ext_vector_type(4)));

#define GLOAD_LDS16(gp, lp)                                              \
    __builtin_amdgcn_global_load_lds(                                    \
        (const __attribute__((address_space(1))) unsigned int*)(gp),     \
        (__attribute__((address_space(3))) unsigned int*)(lp), 16, 0, 0)

// wmid chain (continuous): ramp [0,a), 1 [a,b], down (b,c), 0 [c,d], tail >d.
// tail = -1 + 2^(1 - t/d) (k = ln2/d). down = 1-(t-b)/(c-b) folded into fma.

__device__ __forceinline__ float loss_head(float p, float t) {
    int ap = (p>=150.0f)+(p>=500.0f)+(p>=1000.0f)+(p>=1800.0f)+(p>=2600.0f);
    int at = (t>=150.0f)+(t>=500.0f)+(t>=1000.0f)+(t>=1800.0f)+(t>=2600.0f);
    float wc = exp2f(fabsf((float)(ap-at)) * 0.13750352374993502f); // 1.1^|d|
    float wm = fmaxf(fminf(fminf(t*0.0125f, 1.0f), fmaf(t,-0.004f,7.0f)), 0.0f);
    float tail = exp2f(fmaf(t,-0.0005f,1.0f)) - 1.0f;
    wm = (t>2000.0f) ? tail : wm;
    wm += (p<0.0f) ? 2.0f : 1.0f;
    return fabsf(p-t)*wc*wm;
}

// AIS compare in scaled space: p*rs >= thr  <=>  p >= thr*s (rs = 1/s, v_rcp).
// wmid uses RAW t (reference scales only the AIS thresholds).
__device__ __forceinline__ float loss_chest(float p, float t, float rs) {
    float ps = p*rs, ts = t*rs;
    int ap = (ps>=22.0f)+(ps>=35.0f)+(ps>=45.0f)+(ps>=55.0f)+(ps>=65.0f);
    int at = (ts>=22.0f)+(ts>=35.0f)+(ts>=45.0f)+(ts>=55.0f)+(ts>=65.0f);
    float wc = exp2f(fabsf((float)(ap-at)) * 0.13750352374993502f);
    float wm = fmaxf(fminf(fminf(t*0.1f, 1.0f), fmaf(t,-0.1f,8.5f)), 0.0f);
    float tail = exp2f(fmaf(t,-0.01f,1.0f)) - 1.0f;
    wm = (t>100.0f) ? tail : wm;
    wm += (p<0.0f) ? 2.0f : 1.0f;
    return fabsf(p-t)*wc*wm;
}

__device__ __forceinline__ float loss_neck(float p, float t) {
    int ap = (p>=0.2f)+(p>=0.5f)+(p>=1.0f)+(p>=1.5f)+(p>=2.0f);
    int at = (t>=0.2f)+(t>=0.5f)+(t>=1.0f)+(t>=1.5f)+(t>=2.0f);
    float wc = exp2f(fabsf((float)(ap-at)) * 0.13750352374993502f);
    float wm = fmaxf(fminf(fminf(t*6.6666667f, 1.0f), fmaf(t,-5.0f,8.5f)), 0.0f);
    float tail = exp2f(fmaf(t,-0.52631579f,1.0f)) - 1.0f;
    wm = (t>1.9f) ? tail : wm;
    wm += (p<0.0f) ? 2.0f : 1.0f;
    return fabsf(p-t)*wc*wm;
}

// 4 rows = 3 vf4 of pred/true + 1 vi4 of ot. Fixed slot roles:
// p0=(h,d,n,h) p1=(d,n,h,d) p2=(n,h,d,n)
__device__ __forceinline__ float quad_loss(vf4 p0, vf4 p1, vf4 p2,
                                           vf4 t0, vf4 t1, vf4 t2,
                                           vi4 o) {
    float r0 = __builtin_amdgcn_rcpf(fmaf(0.1f,(float)o.x,0.8f));
    float r1 = __builtin_amdgcn_rcpf(fmaf(0.1f,(float)o.y,0.8f));
    float r2 = __builtin_amdgcn_rcpf(fmaf(0.1f,(float)o.z,0.8f));
    float r3 = __builtin_amdgcn_rcpf(fmaf(0.1f,(float)o.w,0.8f));
    float a;
    a  = loss_head (p0.x,t0.x) + loss_chest(p0.y,t0.y,r0) + loss_neck(p0.z,t0.z);
    a += loss_head (p0.w,t0.w) + loss_chest(p1.x,t1.x,r1) + loss_neck(p1.y,t1.y);
    a += loss_head (p1.z,t1.z) + loss_chest(p1.w,t1.w,r2) + loss_neck(p2.x,t2.x);
    a += loss_head (p2.y,t2.y) + loss_chest(p2.z,t2.z,r3) + loss_neck(p2.w,t2.w);
    return a;
}

__global__ __launch_bounds__(NT)
void weighted_loss_main(const float* __restrict__ pred,
                        const float* __restrict__ truth,
                        const int*   __restrict__ ot,
                        float* __restrict__ partial, int B) {
    const int nquad = B >> 2;
    const int tid   = threadIdx.x;
    const int qBase = blockIdx.x * NT;
    const int T     = gridDim.x * NT;
    const vf4* p4 = (const vf4*)pred;
    const vf4* t4 = (const vf4*)truth;
    const vi4* o4 = (const vi4*)ot;

    __shared__ vf4 lds_p[3 * NT];   // 12 KB
    __shared__ vf4 lds_t[3 * NT];   // 12 KB

    float acc = 0.0f;

    if (qBase + NT <= nquad) {      // full block: hot path (always, for B=4M)
        const int vBase = qBase * 3;            // first vf4 of this block
        // 6x global_load_lds, 16B/lane, unit stride across the block.
        // LDS dest linear in lane: base + lane*16 per wave (m104-safe).
        #pragma unroll
        for (int k = 0; k < 3; ++k) {
            GLOAD_LDS16(&p4[vBase + k*NT + tid], &lds_p[k*NT + tid]);
            GLOAD_LDS16(&t4[vBase + k*NT + tid], &lds_t[k*NT + tid]);
        }
        vi4 o = __builtin_nontemporal_load(&o4[qBase + tid]);
        asm volatile("s_waitcnt vmcnt(0)" ::: "memory");
        __syncthreads();
        vf4 p0 = lds_p[3*tid+0], p1 = lds_p[3*tid+1], p2 = lds_p[3*tid+2];
        vf4 t0 = lds_t[3*tid+0], t1 = lds_t[3*tid+1], t2 = lds_t[3*tid+2];
        acc = quad_loss(p0,p1,p2, t0,t1,t2, o);
    } else {                        // cold: partial last block (B not 4M*4)
        for (int q = qBase + tid; q < nquad; q += T) {
            vf4 p0 = p4[3*q], p1 = p4[3*q+1], p2 = p4[3*q+2];
            vf4 t0 = t4[3*q], t1 = t4[3*q+1], t2 = t4[3*q+2];
            vi4 o  = o4[q];
            acc += quad_loss(p0,p1,p2, t0,t1,t2, o);
        }
    }
    // row tail (B not multiple of 4) — empty for B=4M
    for (int r = (nquad<<2) + qBase + tid; r < B; r += T) {
        float rs = __builtin_amdgcn_rcpf(fmaf(0.1f,(float)ot[r],0.8f));
        acc += loss_head (pred[3*r],   truth[3*r])
             + loss_chest(pred[3*r+1], truth[3*r+1], rs)
             + loss_neck (pred[3*r+2], truth[3*r+2]);
    }

    // wave (64) reduce then cross-wave via LDS
    #pragma unroll
    for (int off = 32; off > 0; off >>= 1) acc += __shfl_down(acc, off, 64);
    __shared__ float sm[NT / 64];
    const int lane = threadIdx.x & 63, wid = threadIdx.x >> 6;
    if (lane == 0) sm[wid] = acc;
    __syncthreads();
    if (threadIdx.x == 0) {
        float s = 0.0f;
        #pragma unroll
        for (int w = 0; w < NT / 64; ++w) s += sm[w];
        partial[blockIdx.x] = s;
    }
}

__global__ __launch_bounds__(1024)
void weighted_loss_reduce(const float* __restrict__ partial, int n,
                          float* __restrict__ out, float invB) {
    float acc = 0.0f;
    for (int i = threadIdx.x; i < n; i += blockDim.x) acc += partial[i];
    #pragma unroll
    for (int off = 32; off > 0; off >>= 1) acc += __shfl_down(acc, off, 64);
    __shared__ float sm[16];
    const int lane = threadIdx.x & 63, wid = threadIdx.x >> 6;
    if (lane == 0) sm[wid] = acc;
    __syncthreads();
    if (threadIdx.x == 0) {
        float s = 0.0f;
        #pragma unroll
        for (int w = 0; w < 16; ++w) s += sm[w];
        out[0] = s * invB;
    }
}

extern "C" void kernel_launch(void* const* d_in, const int* in_sizes, int n_in,
                              void* d_out, int out_size, void* d_ws, size_t ws_size,
                              hipStream_t stream) {
    const float* pred  = (const float*)d_in[0];   // (B,3) f32
    const float* truth = (const float*)d_in[1];   // (B,3) f32
    const int*   ot    = (const int*)d_in[2];     // (B,)  i32
    const int B = in_sizes[2];
    float* partial = (float*)d_ws;                // NB floats, fully overwritten

    weighted_loss_main<<<NB, NT, 0, stream>>>(pred, truth, ot, partial, B);
    weighted_loss_reduce<<<1, 1024, 0, stream>>>(partial, NB, (float*)d_out,
                                                 1.0f / (float)B);
}